// Round 5
// baseline (38.059 us; speedup 1.0000x reference)
//
#include <hip/hip_runtime.h>
#include <stdint.h>

#define B_ 32
#define N_ 1024
#define D_ 512
#define G_ 32

typedef __attribute__((ext_vector_type(8))) short short8;
typedef __attribute__((ext_vector_type(4))) float f32x4;
union U4S8 { uint4 u; short8 s; };

// ws float-offsets:
//   [0, 524288)        : piT bf16 [32 b][32 g][1024 n] (u32 pairs) = 2 MB
//   WS_DN  [+32768)    : K1 denom partials, 1024 blocks x 32 g
//   WS_WF  [+8192)     : W bf16 frag-layout (2048 uint4 = 32 KB)
#define WS_DN  524288
#define WS_WF  557056

__device__ inline uint32_t pack_bf16x2(float a, float b) {
  uint32_t ua = __float_as_uint(a);
  uint32_t ub = __float_as_uint(b);
  ua += 0x7FFFu + ((ua >> 16) & 1u);
  ub += 0x7FFFu + ((ub >> 16) & 1u);
  return (ua >> 16) | (ub & 0xFFFF0000u);
}
__device__ inline uint16_t bf16r(float a) {
  uint32_t u = __float_as_uint(a);
  u += 0x7FFFu + ((u >> 16) & 1u);
  return (uint16_t)(u >> 16);
}

// ---------------- K0: pre-pack W into bf16 frag layout ----------------------
// slot s: g = s>>6, d0 = (s&63)*8 ; dst uint4 index = (ks*4+ksub)*32 + g
// holding W[g][d0..d0+8) packed bf16 low->high.
__global__ __launch_bounds__(256) void mdn_k0(
    const float* __restrict__ W, float* ws)
{
  int s = blockIdx.x * 256 + threadIdx.x;     // 0..2047
  int g = s >> 6;
  int d0 = (s & 63) * 8;
  const float4* src = (const float4*)(W + g * D_ + d0);
  float4 f0 = src[0], f1 = src[1];
  int ks = d0 >> 5, ksub = (d0 >> 3) & 3;
  uint4 v;
  v.x = pack_bf16x2(f0.x, f0.y); v.y = pack_bf16x2(f0.z, f0.w);
  v.z = pack_bf16x2(f1.x, f1.y); v.w = pack_bf16x2(f1.z, f1.w);
  ((uint4*)(ws + WS_WF))[(ks * 4 + ksub) * 32 + g] = v;
}

// ---------------- K1: logits MFMA + in-register softmax ---------------------
// 1024 blocks x 128 thr (2 waves x 16 rows = 32 rows/block, 4 blocks/CU).
// x streamed direct-to-reg; W-frags direct from pre-packed ws (L2-hot).
__global__ __launch_bounds__(128, 2) void mdn_k1(
    const float* __restrict__ x, const float* __restrict__ bpi, float* ws)
{
  __shared__ uint32_t SPT[512];     // piT bf16 [32 g][32 r] = 2 KB
  __shared__ float wpart[2][32];

  const int t = threadIdx.x;
  const int bid = blockIdx.x;
  const int b = bid >> 5;
  const int n0 = (bid & 31) * 32;
  const int w = t >> 6;
  const int lane = t & 63;

  const float* abase =
      x + ((size_t)(b * N_ + n0 + w * 16 + (lane & 15))) * D_ + (lane >> 4) * 8;
  const uint4* wf4 = (const uint4*)(ws + WS_WF);

  f32x4 acc0 = {0.f, 0.f, 0.f, 0.f};
  f32x4 acc1 = {0.f, 0.f, 0.f, 0.f};

  #pragma unroll
  for (int h = 0; h < 2; ++h) {
    float4 fa[8], fb[8];
    #pragma unroll
    for (int k = 0; k < 8; ++k) {
      const float* s = abase + (h * 8 + k) * 32;
      fa[k] = *(const float4*)s; fb[k] = *(const float4*)(s + 4);
    }
    #pragma unroll
    for (int k = 0; k < 8; ++k) {
      int ks = h * 8 + k;
      U4S8 a;
      a.u.x = pack_bf16x2(fa[k].x, fa[k].y);
      a.u.y = pack_bf16x2(fa[k].z, fa[k].w);
      a.u.z = pack_bf16x2(fb[k].x, fb[k].y);
      a.u.w = pack_bf16x2(fb[k].z, fb[k].w);
      int wi = (ks * 4 + (lane >> 4)) * 32 + (lane & 15);
      U4S8 w0, w1;
      w0.u = wf4[wi];
      w1.u = wf4[wi + 16];
      acc0 = __builtin_amdgcn_mfma_f32_16x16x32_bf16(a.s, w0.s, acc0, 0, 0, 0);
      acc1 = __builtin_amdgcn_mfma_f32_16x16x32_bf16(a.s, w1.s, acc1, 0, 0, 0);
    }
  }

  // bias + in-register softmax. C layout: g = lane&15 (acc0) / +16 (acc1),
  // row = w*16 + (lane>>4)*4 + j. Each row lives in one 16-lane group.
  float bs0 = bpi[lane & 15], bs1 = bpi[16 + (lane & 15)];
  float pi0[4], pi1[4];
  float dsum0 = 0.f, dsum1 = 0.f;
  #pragma unroll
  for (int j = 0; j < 4; ++j) {
    float v0 = acc0[j] + bs0, v1 = acc1[j] + bs1;
    float m = fmaxf(v0, v1);
    m = fmaxf(m, __shfl_xor(m, 1));
    m = fmaxf(m, __shfl_xor(m, 2));
    m = fmaxf(m, __shfl_xor(m, 4));
    m = fmaxf(m, __shfl_xor(m, 8));
    float e0 = __expf(v0 - m), e1 = __expf(v1 - m);
    float s = e0 + e1;
    s += __shfl_xor(s, 1); s += __shfl_xor(s, 2);
    s += __shfl_xor(s, 4); s += __shfl_xor(s, 8);
    float inv = 1.0f / s;
    pi0[j] = e0 * inv; pi1[j] = e1 * inv;
    dsum0 += pi0[j];   dsum1 += pi1[j];
  }
  dsum0 += __shfl_xor(dsum0, 16); dsum0 += __shfl_xor(dsum0, 32);
  dsum1 += __shfl_xor(dsum1, 16); dsum1 += __shfl_xor(dsum1, 32);
  if (lane < 16) { wpart[w][lane] = dsum0; wpart[w][16 + lane] = dsum1; }

  {
    uint16_t* sp16 = (uint16_t*)SPT;
    int rl = w * 16 + (lane >> 4) * 4;
    #pragma unroll
    for (int j = 0; j < 4; ++j) {
      sp16[(lane & 15) * 32 + rl + j] = bf16r(pi0[j]);
      sp16[(16 + (lane & 15)) * 32 + rl + j] = bf16r(pi1[j]);
    }
  }
  __syncthreads();

  // piT global write: [b][g][n] bf16, this block's 32-n slice
  {
    int g = t >> 2, i = t & 3;
    uint4 v = *(uint4*)(SPT + g * 16 + i * 4);
    *(uint4*)((uint32_t*)ws + (size_t)(b * 32 + g) * 512 + (n0 >> 1) + i * 4) = v;
  }
  if (t < 32) {
    ws[WS_DN + bid * 32 + t] = wpart[0][t] + wpart[1][t];
  }
}

// ---------------- K2: moments GEMM + in-kernel finalize ---------------------
// 256 blocks x 512 thr: block = (b, q 32-col chunk). 8 waves: kh = w>>1
// (256-row K-slice), ot = w&1 (16-col tile). LDS reduce over kh, finalize,
// write final weights/scales/locs. No partials, no K3.
__global__ __launch_bounds__(512, 2) void mdn_k2(
    const float* __restrict__ x, float* ws, float* __restrict__ out)
{
  __shared__ float dnm[G_];
  __shared__ float RED[4][2][32][16][2];   // 32 KB

  const int t = threadIdx.x;
  const int bid = blockIdx.x;
  const int b = bid >> 3;
  const int q = bid & 7;
  const int w = t >> 6;
  const int lane = t & 63;
  const int kh = w >> 1;      // 0..3 : 256-row K slice
  const int ot = w & 1;       // 16-col tile within the 32-col chunk

  if (t < G_) {               // denom sum (+ weights from the q==0 block)
    float s = 0.f;
    #pragma unroll
    for (int c = 0; c < 32; ++c) s += ws[WS_DN + (b * 32 + c) * 32 + t];
    dnm[t] = s;
    if (q == 0) out[b * G_ + t] = s * (1.0f / 1024.0f);
  }

  const uint32_t* piT = (const uint32_t*)ws;
  const uint32_t* pa0 =
      piT + (size_t)(b * 32 + (lane & 15)) * 512 + kh * 128 + (lane >> 4) * 4;
  const uint32_t* pa1 = pa0 + 16 * 512;

  const int ocol = q * 32 + ot * 16 + (lane & 15);
  const float* xb =
      x + ((size_t)(b * N_) + kh * 256 + (lane >> 4) * 8) * D_ + ocol;

  f32x4 aM10 = {0.f,0.f,0.f,0.f}, aM11 = {0.f,0.f,0.f,0.f};
  f32x4 aM20 = {0.f,0.f,0.f,0.f}, aM21 = {0.f,0.f,0.f,0.f};

  #pragma unroll
  for (int ks = 0; ks < 8; ++ks) {
    U4S8 A0, A1;
    A0.u = *(const uint4*)(pa0 + ks * 16);
    A1.u = *(const uint4*)(pa1 + ks * 16);
    const float* xp = xb + (size_t)ks * 32 * D_;
    float mu[8], sg[8];
    #pragma unroll
    for (int i = 0; i < 8; ++i) {
      mu[i] = xp[i * D_];
      sg[i] = xp[i * D_ + 256];
    }
    U4S8 Bm, B2;
    Bm.u.x = pack_bf16x2(mu[0], mu[1]); Bm.u.y = pack_bf16x2(mu[2], mu[3]);
    Bm.u.z = pack_bf16x2(mu[4], mu[5]); Bm.u.w = pack_bf16x2(mu[6], mu[7]);
    float u0 = fmaf(mu[0], mu[0], sg[0] * sg[0]);
    float u1 = fmaf(mu[1], mu[1], sg[1] * sg[1]);
    float u2 = fmaf(mu[2], mu[2], sg[2] * sg[2]);
    float u3 = fmaf(mu[3], mu[3], sg[3] * sg[3]);
    float u4 = fmaf(mu[4], mu[4], sg[4] * sg[4]);
    float u5 = fmaf(mu[5], mu[5], sg[5] * sg[5]);
    float u6 = fmaf(mu[6], mu[6], sg[6] * sg[6]);
    float u7 = fmaf(mu[7], mu[7], sg[7] * sg[7]);
    B2.u.x = pack_bf16x2(u0, u1); B2.u.y = pack_bf16x2(u2, u3);
    B2.u.z = pack_bf16x2(u4, u5); B2.u.w = pack_bf16x2(u6, u7);
    aM10 = __builtin_amdgcn_mfma_f32_16x16x32_bf16(A0.s, Bm.s, aM10, 0, 0, 0);
    aM11 = __builtin_amdgcn_mfma_f32_16x16x32_bf16(A1.s, Bm.s, aM11, 0, 0, 0);
    aM20 = __builtin_amdgcn_mfma_f32_16x16x32_bf16(A0.s, B2.s, aM20, 0, 0, 0);
    aM21 = __builtin_amdgcn_mfma_f32_16x16x32_bf16(A1.s, B2.s, aM21, 0, 0, 0);
  }

  // park per-wave results in LDS: RED[kh][ot][g][col16][m1|m2]
  #pragma unroll
  for (int j = 0; j < 4; ++j) {
    int g0 = (lane >> 4) * 4 + j;
    int cl = lane & 15;
    RED[kh][ot][g0][cl][0] = aM10[j];
    RED[kh][ot][g0][cl][1] = aM20[j];
    RED[kh][ot][16 + g0][cl][0] = aM11[j];
    RED[kh][ot][16 + g0][cl][1] = aM21[j];
  }
  __syncthreads();

  if (t < 256) {
    int g = t >> 3;
    int col = (t & 7) * 4;          // 4 cols within the 32-col chunk
    float inv = 1.0f / dnm[g];
    float lc4[4], sc4[4];
    #pragma unroll
    for (int cc = 0; cc < 4; ++cc) {
      int colc = col + cc;
      int o2 = colc >> 4, cl = colc & 15;
      float m1 = RED[0][o2][g][cl][0] + RED[1][o2][g][cl][0] +
                 RED[2][o2][g][cl][0] + RED[3][o2][g][cl][0];
      float m2 = RED[0][o2][g][cl][1] + RED[1][o2][g][cl][1] +
                 RED[2][o2][g][cl][1] + RED[3][o2][g][cl][1];
      float lc = m1 * inv;
      lc4[cc] = lc;
      sc4[cc] = sqrtf(fmaxf(m2 * inv - lc * lc, 0.f));
    }
    float* scales = out + 1024;
    float* locs = out + 1024 + 262144;
    int oi = ((b * G_ + g) << 8) + q * 32 + col;
    *(float4*)(scales + oi) = make_float4(sc4[0], sc4[1], sc4[2], sc4[3]);
    *(float4*)(locs + oi)   = make_float4(lc4[0], lc4[1], lc4[2], lc4[3]);
  }
}

extern "C" void kernel_launch(void* const* d_in, const int* in_sizes, int n_in,
                              void* d_out, int out_size, void* d_ws, size_t ws_size,
                              hipStream_t stream)
{
  const float* x = (const float*)d_in[0];
  const float* W = (const float*)d_in[1];
  const float* bpi = (const float*)d_in[2];
  float* out = (float*)d_out;
  float* ws = (float*)d_ws;
  hipLaunchKernelGGL(mdn_k0, dim3(8), dim3(256), 0, stream, W, ws);
  hipLaunchKernelGGL(mdn_k1, dim3(1024), dim3(128), 0, stream, x, bpi, ws);
  hipLaunchKernelGGL(mdn_k2, dim3(256), dim3(512), 0, stream, x, ws, out);
}